// Round 4
// baseline (537.658 us; speedup 1.0000x reference)
//
#include <hip/hip_runtime.h>

// FFLayer: out = relu( (x / (||x||_2 + 1e-4)) @ W^T + b )
// x: [131072,1024] f32, W: [256,1024] f32, b: [256] f32, out: [131072,256] f32
//
// Round 4: ZERO-LDS, ZERO-BARRIER K-loop.
//  - A (x) loaded per-wave directly from HBM into MFMA fragment layout
//    (lane rm=row, q*8 k-granule: 32B/lane, 128B/row contiguous per wave).
//  - B (bf16 W in d_ws, 512KB) loaded per-wave directly from L2.
//  - Wave owns 32 rows x 64 cols (acc=32 VGPRs); 8 waves -> BM=64, 2048 blocks.
//    B L2 redundancy: 16384 waves * 128KB = 2.1 GB ~= 19 TB/s < L2 ceiling.
//  - Fully unrolled 32 K-steps, no fences -> compiler free to hoist loads.
//  - sumsq lane-local (fixed rows), shfl_xor reduce; LDS used only in the
//    epilogue (transpose for fully-coalesced 128B stores).

#define IN_F   1024
#define OUT_F  256
#define BATCH  131072
#define BM     64
#define NKS    32      // K-steps of 32 (mfma 16x16x32)
#define EPSV   1e-4f

typedef __attribute__((ext_vector_type(8))) __bf16 bf16x8;
typedef __attribute__((ext_vector_type(4))) __bf16 bf16x4;
typedef __attribute__((ext_vector_type(4))) float  f32x4;

// W (f32 [256][1024]) -> bf16 [256][1024] in d_ws (512 KB)
__global__ void wconv_kernel(const float* __restrict__ W, __bf16* __restrict__ Wb) {
  const int t = blockIdx.x * blockDim.x + threadIdx.x;
  const float4 v = reinterpret_cast<const float4*>(W)[t];
  bf16x4 h;
  h[0] = (__bf16)v.x; h[1] = (__bf16)v.y; h[2] = (__bf16)v.z; h[3] = (__bf16)v.w;
  reinterpret_cast<bf16x4*>(Wb)[t] = h;
}

__global__ __launch_bounds__(512, 4)
void ffl_kernel(const float* __restrict__ x, const __bf16* __restrict__ Wb,
                const float* __restrict__ bias, float* __restrict__ out) {
  __shared__ char smem[67072];   // epilogue only: [64][260] f32 + norms[64]

  const int tid  = threadIdx.x;
  const int lane = tid & 63;
  const int wave = tid >> 6;     // 8 waves: 2(M) x 4(N)
  const int wr   = wave >> 2;    // row-group (32 rows)
  const int wc   = wave & 3;     // col-quarter (64 cols)
  const int rm   = lane & 15;
  const int q    = lane >> 4;
  const size_t block_row = (size_t)blockIdx.x * BM;

  // A fragment pointers: lane reads row (base + m*16 + rm), 8 f32 at k = kt*32 + q*8
  const float* ap0 = x + (block_row + wr * 32 + rm) * IN_F + q * 8;
  const float* ap1 = ap0 + 16 * IN_F;
  // B fragment pointer: lane reads W-row (wc*64 + n*16 + rm), 8 bf16 at same k
  const __bf16* bp = Wb + (size_t)(wc * 64 + rm) * IN_F + q * 8;

  f32x4 acc[2][4];
  #pragma unroll
  for (int m = 0; m < 2; ++m)
    #pragma unroll
    for (int n = 0; n < 4; ++n)
      acc[m][n] = (f32x4){0.f, 0.f, 0.f, 0.f};

  float ssq0 = 0.f, ssq1 = 0.f;

  #pragma unroll
  for (int kt = 0; kt < NKS; ++kt) {
    const int ko = kt * 32;

    const f32x4 a0lo = *reinterpret_cast<const f32x4*>(ap0 + ko);
    const f32x4 a0hi = *reinterpret_cast<const f32x4*>(ap0 + ko + 4);
    const f32x4 a1lo = *reinterpret_cast<const f32x4*>(ap1 + ko);
    const f32x4 a1hi = *reinterpret_cast<const f32x4*>(ap1 + ko + 4);

    bf16x8 bF[4];
    #pragma unroll
    for (int n = 0; n < 4; ++n)
      bF[n] = *reinterpret_cast<const bf16x8*>(bp + (size_t)n * 16 * IN_F + ko);

    ssq0 += a0lo[0]*a0lo[0] + a0lo[1]*a0lo[1] + a0lo[2]*a0lo[2] + a0lo[3]*a0lo[3]
          + a0hi[0]*a0hi[0] + a0hi[1]*a0hi[1] + a0hi[2]*a0hi[2] + a0hi[3]*a0hi[3];
    ssq1 += a1lo[0]*a1lo[0] + a1lo[1]*a1lo[1] + a1lo[2]*a1lo[2] + a1lo[3]*a1lo[3]
          + a1hi[0]*a1hi[0] + a1hi[1]*a1hi[1] + a1hi[2]*a1hi[2] + a1hi[3]*a1hi[3];

    bf16x8 aF0, aF1;
    aF0[0]=(__bf16)a0lo[0]; aF0[1]=(__bf16)a0lo[1]; aF0[2]=(__bf16)a0lo[2]; aF0[3]=(__bf16)a0lo[3];
    aF0[4]=(__bf16)a0hi[0]; aF0[5]=(__bf16)a0hi[1]; aF0[6]=(__bf16)a0hi[2]; aF0[7]=(__bf16)a0hi[3];
    aF1[0]=(__bf16)a1lo[0]; aF1[1]=(__bf16)a1lo[1]; aF1[2]=(__bf16)a1lo[2]; aF1[3]=(__bf16)a1lo[3];
    aF1[4]=(__bf16)a1hi[0]; aF1[5]=(__bf16)a1hi[1]; aF1[6]=(__bf16)a1hi[2]; aF1[7]=(__bf16)a1hi[3];

    #pragma unroll
    for (int n = 0; n < 4; ++n) {
      acc[0][n] = __builtin_amdgcn_mfma_f32_16x16x32_bf16(aF0, bF[n], acc[0][n], 0, 0, 0);
      acc[1][n] = __builtin_amdgcn_mfma_f32_16x16x32_bf16(aF1, bF[n], acc[1][n], 0, 0, 0);
    }
  }

  // ---- row L2-norms: reduce lane partials across the 4 q-groups
  ssq0 += __shfl_xor(ssq0, 16); ssq0 += __shfl_xor(ssq0, 32);
  ssq1 += __shfl_xor(ssq1, 16); ssq1 += __shfl_xor(ssq1, 32);
  float* norms = reinterpret_cast<float*>(smem + 66560);
  if (q == 0 && wc == 0) {
    norms[wr * 32 + rm]      = 1.0f / (sqrtf(ssq0) + EPSV);
    norms[wr * 32 + 16 + rm] = 1.0f / (sqrtf(ssq1) + EPSV);
  }
  __syncthreads();

  // ---- scale + bias + relu, stage to LDS (transpose for coalesced stores)
  float* stg = reinterpret_cast<float*>(smem);   // [64][260] f32
  const int col0 = wc * 64 + rm;
  #pragma unroll
  for (int n = 0; n < 4; ++n) {
    const float bn = bias[col0 + n * 16];
    #pragma unroll
    for (int m = 0; m < 2; ++m) {
      #pragma unroll
      for (int j = 0; j < 4; ++j) {
        const int lr = wr * 32 + m * 16 + q * 4 + j;
        stg[lr * 260 + col0 + n * 16] = fmaxf(acc[m][n][j] * norms[lr] + bn, 0.f);
      }
    }
  }
  __syncthreads();

  // ---- coalesced store: 8 rows/wave, full 128B lines
  const int r = tid >> 3, p = tid & 7;
  const float* srow = stg + r * 260;
  float* orow = out + (block_row + r) * OUT_F;
  #pragma unroll
  for (int i = 0; i < 8; ++i) {
    const int f = i * 8 + p;
    const f32x4 v = *reinterpret_cast<const f32x4*>(srow + f * 4);
    *reinterpret_cast<f32x4*>(orow + f * 4) = v;
  }
}

extern "C" void kernel_launch(void* const* d_in, const int* in_sizes, int n_in,
                              void* d_out, int out_size, void* d_ws, size_t ws_size,
                              hipStream_t stream) {
  const float* x = (const float*)d_in[0];
  const float* W = (const float*)d_in[1];
  const float* b = (const float*)d_in[2];
  float* out = (float*)d_out;
  __bf16* Wb = (__bf16*)d_ws;   // 512 KB scratch

  wconv_kernel<<<(OUT_F * IN_F / 4) / 256, 256, 0, stream>>>(W, Wb);
  ffl_kernel<<<BATCH / BM, 512, 0, stream>>>(x, Wb, b, out);
}

// Round 5
// 200.397 us; speedup vs baseline: 2.6830x; 2.6830x over previous
//
#include <hip/hip_runtime.h>

// FFLayer: out = relu( (x / (||x||_2 + 1e-4)) @ W^T + b )
// x: [131072,1024] f32, W: [256,1024] f32, b: [256] f32, out: [131072,256] f32
//
// Round 5: m201-discipline pipeline, ALL staging via global_load_lds (no
// asm result registers -> nothing for regalloc to corrupt, nothing for the
// scheduler to sink). Triple-buffered A(f32,8KB)+B(bf16,16KB), BK=32,
// counted s_waitcnt vmcnt(3) before each raw s_barrier (never 0 mid-loop):
// one full tile (24KB/block) stays in flight across every barrier.
// sumsq computed exactly (f32) from LDS during compute; bf16 cvt in-register.
// Both LDS tiles XOR-swizzled on both sides (pre-swizzled global source +
// swizzled ds_read) -> 2-way (free) bank conflicts.

#define IN_F   1024
#define OUT_F  256
#define BATCH  131072
#define BM     64
#define BK     32
#define NKT    32
#define EPSV   1e-4f

typedef __attribute__((ext_vector_type(8))) __bf16 bf16x8;
typedef __attribute__((ext_vector_type(4))) __bf16 bf16x4;
typedef __attribute__((ext_vector_type(4))) float  f32x4;

__device__ __forceinline__ void gload_lds16(const void* g, void* lds) {
  __builtin_amdgcn_global_load_lds(
      (const __attribute__((address_space(1))) void*)g,
      (__attribute__((address_space(3))) void*)lds, 16, 0, 0);
}

#define VM_WAIT(N) do { asm volatile("s_waitcnt vmcnt(" #N ")" ::: "memory"); \
                        __builtin_amdgcn_sched_barrier(0); } while (0)

// W (f32 [256][1024]) -> bf16 [256][1024] in d_ws (512 KB)
__global__ void wconv_kernel(const float* __restrict__ W, __bf16* __restrict__ Wb) {
  const int t = blockIdx.x * blockDim.x + threadIdx.x;
  const float4 v = reinterpret_cast<const float4*>(W)[t];
  bf16x4 h;
  h[0] = (__bf16)v.x; h[1] = (__bf16)v.y; h[2] = (__bf16)v.z; h[3] = (__bf16)v.w;
  reinterpret_cast<bf16x4*>(Wb)[t] = h;
}

__global__ __launch_bounds__(512, 4)
void ffl_kernel(const float* __restrict__ x, const __bf16* __restrict__ Wb,
                const float* __restrict__ bias, float* __restrict__ out) {
  // layout: A bufs [0, 24576), B bufs [24576, 73728), norms [73728, 73984)
  __shared__ __align__(16) char smem[73984];
  char* Abuf[3] = {smem, smem + 8192, smem + 16384};
  char* Bbuf[3] = {smem + 24576, smem + 40960, smem + 57344};

  const int tid  = threadIdx.x;
  const int lane = tid & 63;
  const int wave = tid >> 6;     // 8 waves: 2(M) x 4(N)
  const int wr   = wave >> 2;
  const int wc   = wave & 3;
  const int rm   = lane & 15;
  const int q    = lane >> 4;
  const size_t block_row = (size_t)blockIdx.x * BM;

  // ---- A staging (1 gload_lds/thread): wave w -> 1KB chunk = rows 8w..8w+7
  const int arow = 8 * wave + (lane >> 3);          // x row within tile
  const int asg  = (lane & 7) ^ (arow & 7);         // pre-swizzled src granule
  const float* aSrc = x + (block_row + arow) * IN_F + asg * 4;
  const int aDstOff = wave * 1024;                  // uniform wave base

  // ---- B staging (2 gload_lds/thread): chunk 2w+i = 16 rows of 64B
  int   brow[2]; const __bf16* bSrc[2]; int bDstOff[2];
  #pragma unroll
  for (int i = 0; i < 2; ++i) {
    const int c = 2 * wave + i;
    brow[i] = c * 16 + (lane >> 2);
    const int sg = (lane & 3) ^ ((brow[i] >> 1) & 3);
    bSrc[i] = Wb + (size_t)brow[i] * IN_F + sg * 8;
    bDstOff[i] = c * 1024;
  }

  f32x4 acc[2][4];
  #pragma unroll
  for (int m = 0; m < 2; ++m)
    #pragma unroll
    for (int n = 0; n < 4; ++n)
      acc[m][n] = (f32x4){0.f, 0.f, 0.f, 0.f};

  float ssq0 = 0.f, ssq1 = 0.f;

  auto stage = [&](int buf, int kt) {
    gload_lds16(aSrc + kt * BK, Abuf[buf] + aDstOff);
    gload_lds16(bSrc[0] + kt * BK, Bbuf[buf] + bDstOff[0]);
    gload_lds16(bSrc[1] + kt * BK, Bbuf[buf] + bDstOff[1]);
  };

  // ---------------- prologue: tiles 0 and 1 in flight ----------------
  stage(0, 0);
  stage(1, 1);
  VM_WAIT(3);                    // tile 0 landed; tile 1 in flight
  __builtin_amdgcn_s_barrier();

  // ---------------- main loop ----------------
  #pragma unroll
  for (int kt = 0; kt < NKT; ++kt) {
    const int cur = kt % 3;
    if (kt + 2 < NKT) stage((kt + 2) % 3, kt + 2);

    // A fragments: row ra, logical granules 2q, 2q+1 (16B each), f32 -> bf16
    bf16x8 aF[2];
    #pragma unroll
    for (int m = 0; m < 2; ++m) {
      const int ra = wr * 32 + m * 16 + rm;
      const char* ab = Abuf[cur] + ra * 128;
      const int sw = ra & 7;
      const f32x4 lo = *reinterpret_cast<const f32x4*>(ab + ((2 * q)     ^ sw) * 16);
      const f32x4 hi = *reinterpret_cast<const f32x4*>(ab + ((2 * q + 1) ^ sw) * 16);
      float& ssq = m ? ssq1 : ssq0;
      ssq += lo[0]*lo[0] + lo[1]*lo[1] + lo[2]*lo[2] + lo[3]*lo[3]
           + hi[0]*hi[0] + hi[1]*hi[1] + hi[2]*hi[2] + hi[3]*hi[3];
      bf16x8 a;
      a[0]=(__bf16)lo[0]; a[1]=(__bf16)lo[1]; a[2]=(__bf16)lo[2]; a[3]=(__bf16)lo[3];
      a[4]=(__bf16)hi[0]; a[5]=(__bf16)hi[1]; a[6]=(__bf16)hi[2]; a[7]=(__bf16)hi[3];
      aF[m] = a;
    }

    #pragma unroll
    for (int n = 0; n < 4; ++n) {
      const int rb = wc * 64 + n * 16 + rm;
      const bf16x8 bF = *reinterpret_cast<const bf16x8*>(
          Bbuf[cur] + rb * 64 + (q ^ ((rb >> 1) & 3)) * 16);
      acc[0][n] = __builtin_amdgcn_mfma_f32_16x16x32_bf16(aF[0], bF, acc[0][n], 0, 0, 0);
      acc[1][n] = __builtin_amdgcn_mfma_f32_16x16x32_bf16(aF[1], bF, acc[1][n], 0, 0, 0);
    }

    if (kt + 2 < NKT) { VM_WAIT(3); } else { VM_WAIT(0); }
    __builtin_amdgcn_s_barrier();
  }

  // ---------------- row L2-norms: reduce lane partials over q ----------------
  ssq0 += __shfl_xor(ssq0, 16); ssq0 += __shfl_xor(ssq0, 32);
  ssq1 += __shfl_xor(ssq1, 16); ssq1 += __shfl_xor(ssq1, 32);
  float* norms = reinterpret_cast<float*>(smem + 73728);
  if (wc == 0 && q == 0) {
    norms[wr * 32 + rm]      = 1.0f / (sqrtf(ssq0) + EPSV);
    norms[wr * 32 + 16 + rm] = 1.0f / (sqrtf(ssq1) + EPSV);
  }
  __syncthreads();

  // ---------------- scale + bias + relu -> LDS transpose ----------------
  float* stg = reinterpret_cast<float*>(smem);   // [64][260] f32 = 66560 B
  const int col0 = wc * 64 + rm;
  #pragma unroll
  for (int n = 0; n < 4; ++n) {
    const float bn = bias[col0 + n * 16];
    #pragma unroll
    for (int m = 0; m < 2; ++m) {
      #pragma unroll
      for (int j = 0; j < 4; ++j) {
        const int lr = wr * 32 + m * 16 + q * 4 + j;
        stg[lr * 260 + col0 + n * 16] = fmaxf(acc[m][n][j] * norms[lr] + bn, 0.f);
      }
    }
  }
  __syncthreads();

  // ---------------- coalesced store: 8 rows/wave, full 128B lines ----------
  const int r = tid >> 3, p = tid & 7;
  const float* srow = stg + r * 260;
  float* orow = out + (block_row + r) * OUT_F;
  #pragma unroll
  for (int i = 0; i < 8; ++i) {
    const int f = i * 8 + p;
    const f32x4 v = *reinterpret_cast<const f32x4*>(srow + f * 4);
    *reinterpret_cast<f32x4*>(orow + f * 4) = v;
  }
}

extern "C" void kernel_launch(void* const* d_in, const int* in_sizes, int n_in,
                              void* d_out, int out_size, void* d_ws, size_t ws_size,
                              hipStream_t stream) {
  const float* x = (const float*)d_in[0];
  const float* W = (const float*)d_in[1];
  const float* b = (const float*)d_in[2];
  float* out = (float*)d_out;
  __bf16* Wb = (__bf16*)d_ws;   // 512 KB scratch

  wconv_kernel<<<(OUT_F * IN_F / 4) / 256, 256, 0, stream>>>(W, Wb);
  ffl_kernel<<<BATCH / BM, 512, 0, stream>>>(x, Wb, b, out);
}

// Round 6
// 183.392 us; speedup vs baseline: 2.9317x; 1.0927x over previous
//
#include <hip/hip_runtime.h>

// FFLayer: out = relu( (x / (||x||_2 + 1e-4)) @ W^T + b )
// x: [131072,1024] f32, W: [256,1024] f32, b: [256] f32, out: [131072,256] f32
//
// Round 6: r5 discipline (all staging via global_load_lds, triple buffers,
// counted vmcnt, raw s_barrier) scaled up: 1 block/CU, 1024 threads, BM=128,
// 16 waves each owning 32x64 outputs. A staged f32 in BK=64 groups (256B
// contiguous per row), 3 x 32KB; B bf16 per BK=32 step, 3 x 16KB. LDS 144KB.
// Steady-state VM_WAIT(3) per step (FIFO-simulated), tail 1/1/0/0.

#define IN_F   1024
#define OUT_F  256
#define BATCH  131072
#define BM     128
#define NKT    32      // BK=32 compute steps
#define EPSV   1e-4f

typedef __attribute__((ext_vector_type(8))) __bf16 bf16x8;
typedef __attribute__((ext_vector_type(4))) __bf16 bf16x4;
typedef __attribute__((ext_vector_type(4))) float  f32x4;

__device__ __forceinline__ void gload_lds16(const void* g, void* lds) {
  __builtin_amdgcn_global_load_lds(
      (const __attribute__((address_space(1))) void*)g,
      (__attribute__((address_space(3))) void*)lds, 16, 0, 0);
}

#define VM_WAIT(N) do { asm volatile("s_waitcnt vmcnt(" #N ")" ::: "memory"); \
                        __builtin_amdgcn_sched_barrier(0); } while (0)

// W (f32 [256][1024]) -> bf16 [256][1024] in d_ws (512 KB)
__global__ void wconv_kernel(const float* __restrict__ W, __bf16* __restrict__ Wb) {
  const int t = blockIdx.x * blockDim.x + threadIdx.x;
  const float4 v = reinterpret_cast<const float4*>(W)[t];
  bf16x4 h;
  h[0] = (__bf16)v.x; h[1] = (__bf16)v.y; h[2] = (__bf16)v.z; h[3] = (__bf16)v.w;
  reinterpret_cast<bf16x4*>(Wb)[t] = h;
}

__global__ __launch_bounds__(1024, 4)
void ffl_kernel(const float* __restrict__ x, const __bf16* __restrict__ Wb,
                const float* __restrict__ bias, float* __restrict__ out) {
  // A bufs: 3 x 32KB at 0/32768/65536 (f32, [128 rows][256B], granule-swizzled)
  // B bufs: 3 x 16KB at 98304/114688/131072 (bf16, [256 rows][64B], swizzled)
  // norms: 512B at 147456. Epilogue stg [128][260] f32 = 133120B reuses base.
  __shared__ __align__(16) char smem[147968];
  char* const Ab[3] = {smem, smem + 32768, smem + 65536};
  char* const Bb[3] = {smem + 98304, smem + 114688, smem + 131072};

  const int tid  = threadIdx.x;
  const int lane = tid & 63;
  const int wave = tid >> 6;     // 16 waves: 4(M) x 4(N)
  const int wr   = wave >> 2;    // 0..3, rows wr*32..+31
  const int wc   = wave & 3;     // 0..3, cols wc*64..+63
  const int rm   = lane & 15;
  const int q    = lane >> 4;
  const size_t block_row = (size_t)blockIdx.x * BM;

  // ---- A staging: 2 issues/thread/group. Chunk c=2w+i (1KB = 4 rows x 256B).
  //      lane l -> row 4c + (l>>4), granule gl = l&15, src granule gl^(row&7).
  const float* aSrc[2]; int aDst[2];
  #pragma unroll
  for (int i = 0; i < 2; ++i) {
    const int c   = 2 * wave + i;
    const int row = 4 * c + (lane >> 4);
    const int s   = (lane & 15) ^ (row & 7);
    aSrc[i] = x + (block_row + row) * IN_F + s * 4;
    aDst[i] = c * 1024;
  }
  // ---- B staging: 1 issue/thread/step. Chunk = wave (1KB = 16 rows x 64B).
  const int brow = 16 * wave + (lane >> 2);
  const int bs   = (lane & 3) ^ ((brow >> 1) & 3);
  const __bf16* bSrc = Wb + (size_t)brow * IN_F + bs * 8;
  const int bDst = wave * 1024;

  f32x4 acc[2][4];
  #pragma unroll
  for (int m = 0; m < 2; ++m)
    #pragma unroll
    for (int n = 0; n < 4; ++n)
      acc[m][n] = (f32x4){0.f, 0.f, 0.f, 0.f};

  float ssq0 = 0.f, ssq1 = 0.f;

  auto stageA = [&](int g) {      // group g covers k-steps 2g, 2g+1
    gload_lds16(aSrc[0] + g * 64, Ab[g % 3] + aDst[0]);
    gload_lds16(aSrc[1] + g * 64, Ab[g % 3] + aDst[1]);
  };
  auto stageB = [&](int kt) {
    gload_lds16(bSrc + kt * 32, Bb[kt % 3] + bDst);
  };

  // ---------------- prologue: queue [Ag0 x2, B0, Ag1 x2, B1] ----------------
  stageA(0);
  stageB(0);
  stageA(1);
  stageB(1);
  VM_WAIT(3);                    // Ag0 + B0 landed; Ag1, B1 in flight
  __builtin_amdgcn_s_barrier();

  // ---------------- main loop: 32 steps of BK=32 ----------------
  #pragma unroll
  for (int kt = 0; kt < NKT; ++kt) {
    if (kt + 2 < NKT) stageB(kt + 2);
    if ((kt & 1) == 0 && (kt / 2 + 2) < 16) stageA(kt / 2 + 2);

    const char* abuf = Ab[(kt >> 1) % 3];
    const char* bbuf = Bb[kt % 3];
    const int   gb   = (kt & 1) * 8 + 2 * q;   // A granule base within 256B row

    // A fragments (f32 -> bf16) + exact sumsq
    bf16x8 aF[2];
    #pragma unroll
    for (int m = 0; m < 2; ++m) {
      const int ra = wr * 32 + m * 16 + rm;
      const char* ab = abuf + ra * 256;
      const int sw = ra & 7;
      const f32x4 lo = *reinterpret_cast<const f32x4*>(ab + ((gb)     ^ sw) * 16);
      const f32x4 hi = *reinterpret_cast<const f32x4*>(ab + ((gb + 1) ^ sw) * 16);
      float& ssq = m ? ssq1 : ssq0;
      ssq += lo[0]*lo[0] + lo[1]*lo[1] + lo[2]*lo[2] + lo[3]*lo[3]
           + hi[0]*hi[0] + hi[1]*hi[1] + hi[2]*hi[2] + hi[3]*hi[3];
      bf16x8 a;
      a[0]=(__bf16)lo[0]; a[1]=(__bf16)lo[1]; a[2]=(__bf16)lo[2]; a[3]=(__bf16)lo[3];
      a[4]=(__bf16)hi[0]; a[5]=(__bf16)hi[1]; a[6]=(__bf16)hi[2]; a[7]=(__bf16)hi[3];
      aF[m] = a;
    }

    #pragma unroll
    for (int n = 0; n < 4; ++n) {
      const int rb = wc * 64 + n * 16 + rm;
      const bf16x8 bF = *reinterpret_cast<const bf16x8*>(
          bbuf + rb * 64 + (q ^ ((rb >> 1) & 3)) * 16);
      acc[0][n] = __builtin_amdgcn_mfma_f32_16x16x32_bf16(aF[0], bF, acc[0][n], 0, 0, 0);
      acc[1][n] = __builtin_amdgcn_mfma_f32_16x16x32_bf16(aF[1], bF, acc[1][n], 0, 0, 0);
    }

    // FIFO-simulated waits: steady vmcnt(3); tail kt=28,29 -> 1; 30,31 -> 0.
    if (kt < 28)      { VM_WAIT(3); }
    else if (kt < 30) { VM_WAIT(1); }
    else              { VM_WAIT(0); }
    __builtin_amdgcn_s_barrier();
  }

  // ---------------- row L2-norms ----------------
  ssq0 += __shfl_xor(ssq0, 16); ssq0 += __shfl_xor(ssq0, 32);
  ssq1 += __shfl_xor(ssq1, 16); ssq1 += __shfl_xor(ssq1, 32);
  float* norms = reinterpret_cast<float*>(smem + 147456);
  if (wc == 0 && q == 0) {
    norms[wr * 32 + rm]      = 1.0f / (sqrtf(ssq0) + EPSV);
    norms[wr * 32 + 16 + rm] = 1.0f / (sqrtf(ssq1) + EPSV);
  }
  __syncthreads();

  // ---------------- scale + bias + relu -> LDS transpose ----------------
  float* stg = reinterpret_cast<float*>(smem);   // [128][260] f32 = 133120B
  const int col0 = wc * 64 + rm;
  #pragma unroll
  for (int n = 0; n < 4; ++n) {
    const float bn = bias[col0 + n * 16];
    #pragma unroll
    for (int m = 0; m < 2; ++m) {
      #pragma unroll
      for (int j = 0; j < 4; ++j) {
        const int lr = wr * 32 + m * 16 + q * 4 + j;
        stg[lr * 260 + col0 + n * 16] = fmaxf(acc[m][n][j] * norms[lr] + bn, 0.f);
      }
    }
  }
  __syncthreads();

  // ---------------- coalesced store: full 128B lines ----------------
  const int r = tid >> 3, p = tid & 7;       // 128 rows, 8 threads/row
  const float* srow = stg + r * 260;
  float* orow = out + (block_row + r) * OUT_F;
  #pragma unroll
  for (int i = 0; i < 8; ++i) {
    const int f = i * 8 + p;
    const f32x4 v = *reinterpret_cast<const f32x4*>(srow + f * 4);
    *reinterpret_cast<f32x4*>(orow + f * 4) = v;
  }
}

extern "C" void kernel_launch(void* const* d_in, const int* in_sizes, int n_in,
                              void* d_out, int out_size, void* d_ws, size_t ws_size,
                              hipStream_t stream) {
  const float* x = (const float*)d_in[0];
  const float* W = (const float*)d_in[1];
  const float* b = (const float*)d_in[2];
  float* out = (float*)d_out;
  __bf16* Wb = (__bf16*)d_ws;   // 512 KB scratch

  wconv_kernel<<<(OUT_F * IN_F / 4) / 256, 256, 0, stream>>>(W, Wb);
  ffl_kernel<<<BATCH / BM, 1024, 0, stream>>>(x, Wb, b, out);
}